// Round 1
// baseline (456.022 us; speedup 1.0000x reference)
//
#include <hip/hip_runtime.h>
#include <stdint.h>

#define N_ANCH   300000
#define N_CLS    80
#define DET_DIM  85
#define TOPK     1000
#define MAXB     300
#define NMS_THR  0.4f
#define CAP      4096

// ws layout (uint32 units)
#define OFF_SBITS   0          // 300000 u32
#define OFF_HISTA   300032     // 4096 u32
#define OFF_HISTB   304128     // 4096 u32
#define OFF_META    308224     // 64 u32: [0]=B_A [1]=G_A [2]=B_B [3]=G_B [4]=cand_cnt [7]=const zero
#define OFF_CAND    308352     // 4096 u64 = 8192 u32
#define OFF_TOPK    316544     // 1000 u32
#define OFF_BOXK    317568     // 1000 float4 = 4000 u32
#define OFF_MASK    321600     // 16000 u64 = 32000 u32
#define OFF_KEEPL   353600     // 300 int

// ---------------- scores = max over 80 classes + histogram A ----------------
__global__ __launch_bounds__(256) void k_scores(const float4* __restrict__ cls4,
                                                uint32_t* __restrict__ sbits,
                                                uint32_t* __restrict__ histA) {
    __shared__ uint32_t h[4096];
    int tid = threadIdx.x;
    for (int i = tid; i < 4096; i += 256) h[i] = 0;
    __syncthreads();
    int wave = tid >> 6, lane = tid & 63, g = lane >> 2, q = lane & 3;
    int row = blockIdx.x * 64 + wave * 16 + g;
    if (row < N_ANCH) {
        const float4* rp = cls4 + (size_t)row * 20;   // 80 floats = 20 float4
        float m = -1.0f;
        #pragma unroll
        for (int k = 0; k < 5; k++) {
            float4 v = rp[q + k * 4];
            m = fmaxf(m, fmaxf(fmaxf(v.x, v.y), fmaxf(v.z, v.w)));
        }
        m = fmaxf(m, __shfl_xor(m, 1));
        m = fmaxf(m, __shfl_xor(m, 2));
        if (q == 0) {
            uint32_t sb = __float_as_uint(m);   // scores >= 0: bit order == value order
            sbits[row] = sb;
            atomicAdd(&h[sb >> 20], 1u);
        }
    }
    __syncthreads();
    for (int i = tid; i < 4096; i += 256) {
        uint32_t c = h[i];
        if (c) atomicAdd(&histA[i], c);
    }
}

// ------------- find bin B s.t. suffix count crosses K; G = count above -------------
__global__ __launch_bounds__(1024) void k_findthr(const uint32_t* __restrict__ hist,
                                                  const uint32_t* __restrict__ gprev,
                                                  uint32_t Kbase,
                                                  uint32_t* __restrict__ out2) {
    __shared__ uint32_t part[1024];
    int tid = threadIdx.x;
    uint32_t c[4]; uint32_t s = 0;
    #pragma unroll
    for (int k = 0; k < 4; k++) { c[k] = hist[4095 - (tid * 4 + k)]; s += c[k]; }
    part[tid] = s;
    __syncthreads();
    for (int off = 1; off < 1024; off <<= 1) {
        uint32_t v = (tid >= off) ? part[tid - off] : 0;
        __syncthreads();
        part[tid] += v;
        __syncthreads();
    }
    uint32_t incl = part[tid], excl = incl - s;
    uint32_t K = Kbase - *gprev;
    if (excl < K && incl >= K) {
        uint32_t run = excl;
        #pragma unroll
        for (int k = 0; k < 4; k++) {
            uint32_t nr = run + c[k];
            if (run < K && nr >= K) { out2[0] = 4095 - (tid * 4 + k); out2[1] = run; }
            run = nr;
        }
    }
}

// ---------------- level-B histogram (bits[19:8] within bin B_A) ----------------
__global__ __launch_bounds__(256) void k_histB(const uint32_t* __restrict__ sbits,
                                               const uint32_t* __restrict__ meta,
                                               uint32_t* __restrict__ histB) {
    int t = blockIdx.x * 256 + threadIdx.x;
    if (t >= N_ANCH) return;
    uint32_t sb = sbits[t];
    if ((sb >> 20) == meta[0]) atomicAdd(&histB[(sb >> 8) & 0xFFFu], 1u);
}

// ---------------- compact candidates with 24-bit prefix >= T24 ----------------
__global__ __launch_bounds__(256) void k_compact(const uint32_t* __restrict__ sbits,
                                                 const uint32_t* __restrict__ meta,
                                                 unsigned long long* __restrict__ cand,
                                                 uint32_t* __restrict__ cnt) {
    int t = blockIdx.x * 256 + threadIdx.x;
    if (t >= N_ANCH) return;
    uint32_t T24 = (meta[0] << 12) | meta[2];
    uint32_t sb = sbits[t];
    if ((sb >> 8) >= T24) {
        uint32_t p = atomicAdd(cnt, 1u);
        if (p < CAP) cand[p] = ((unsigned long long)sb << 32) | (uint32_t)(~(uint32_t)t);
    }
}

// ---------------- bitonic sort (desc) of candidates; emit topk + gathered boxes ----------------
__global__ __launch_bounds__(1024) void k_sort(const unsigned long long* __restrict__ cand,
                                               const uint32_t* __restrict__ cnt,
                                               uint32_t* __restrict__ topk,
                                               const float4* __restrict__ boxes4,
                                               float4* __restrict__ boxk) {
    __shared__ unsigned long long sk[CAP];
    int tid = threadIdx.x;
    uint32_t C = *cnt; if (C > CAP) C = CAP;
    for (int i = tid; i < CAP; i += 1024) sk[i] = (i < (int)C) ? cand[i] : 0ull;
    __syncthreads();
    for (int k = 2; k <= CAP; k <<= 1) {
        for (int j = k >> 1; j > 0; j >>= 1) {
            for (int i = tid; i < CAP; i += 1024) {
                int ixj = i ^ j;
                if (ixj > i) {
                    unsigned long long a = sk[i], b = sk[ixj];
                    bool desc = ((i & k) == 0);
                    if (desc ? (a < b) : (a > b)) { sk[i] = b; sk[ixj] = a; }
                }
            }
            __syncthreads();
        }
    }
    if (tid < TOPK) {
        unsigned long long key = sk[tid];
        uint32_t idx = ~(uint32_t)(key & 0xFFFFFFFFull);
        topk[tid] = idx;
        boxk[tid] = boxes4[idx];
    }
}

// ---------------- IoU (fp32, no fma contraction, matches reference op order) ----------------
__device__ __forceinline__ float iou_f(float4 a, float4 b) {
    #pragma clang fp contract(off)
    // box = [y1, x1, y2, x2] -> (x,y,z,w)
    float areaA = (a.z - a.x) * (a.w - a.y);
    float areaB = (b.z - b.x) * (b.w - b.y);
    float ih = fminf(a.z, b.z) - fmaxf(a.x, b.x); ih = fmaxf(ih, 0.0f);
    float iw = fminf(a.w, b.w) - fmaxf(a.y, b.y); iw = fmaxf(iw, 0.0f);
    float inter = ih * iw;
    float denom = (areaA + areaB - inter) + 1e-8f;
    return inter / denom;
}

// ---------------- suppression bitmask M[i][w]: bit j = iou(i, w*64+j) > thr ----------------
__global__ __launch_bounds__(256) void k_mask(const float4* __restrict__ boxk,
                                              unsigned long long* __restrict__ M) {
    int tid = threadIdx.x;
    int gw = blockIdx.x * 4 + (tid >> 6);   // global wave id: 1000 rows * 16 words
    int i = gw >> 4, w = gw & 15, jl = tid & 63;
    int j = w * 64 + jl;
    float4 bi = boxk[i];
    float4 bj = boxk[j < TOPK ? j : 0];
    bool ok = (j < TOPK) && (iou_f(bi, bj) > NMS_THR);
    unsigned long long m = __ballot(ok);
    if (jl == 0) M[i * 16 + w] = m;
}

// ---------------- sequential greedy NMS scan (single wave) ----------------
__global__ __launch_bounds__(64) void k_nms(const unsigned long long* __restrict__ M,
                                            int* __restrict__ keepl) {
    __shared__ unsigned long long kept[16];
    __shared__ uint32_t pfx[17];
    int lane = threadIdx.x;
    if (lane < 16) kept[lane] = 0ull;
    __syncthreads();
    for (int c = 0; c < 16; c++) {
        int i = c * 64 + lane;
        unsigned long long pre = 0ull;
        if (i < TOPK) {
            for (int w = 0; w < c; w++) pre |= M[i * 16 + w] & kept[w];  // kept[w<c] is final
        }
        unsigned long long Mic = (i < TOPK) ? M[i * 16 + c] : 0ull;
        unsigned long long pre_mask = __ballot(pre != 0ull);
        unsigned long long kc = 0ull;
        int lim = (c == 15) ? (TOPK - 960) : 64;
        for (int k = 0; k < lim; k++) {     // uniform serial loop, register-only chain
            unsigned int lo = __shfl((unsigned int)(Mic & 0xffffffffull), k);
            unsigned int hi = __shfl((unsigned int)(Mic >> 32), k);
            unsigned long long m = ((unsigned long long)hi << 32) | lo;
            bool sup = ((pre_mask >> k) & 1ull) || ((m & kc) != 0ull);
            if (!sup) kc |= (1ull << k);
        }
        if (lane == 0) kept[c] = kc;
        __syncthreads();
    }
    if (lane == 0) {
        uint32_t r = 0;
        for (int w = 0; w < 16; w++) { pfx[w] = r; r += __popcll(kept[w]); }
        pfx[16] = r;
    }
    __syncthreads();
    int total = (int)pfx[16]; if (total > MAXB) total = MAXB;
    for (int r = total + lane; r < MAXB; r += 64) keepl[r] = -1;   // disjoint from rank writes
    for (int i = lane; i < TOPK; i += 64) {
        int w = i >> 6, b = i & 63;
        unsigned long long kw = kept[w];
        if ((kw >> b) & 1ull) {
            uint32_t rank = pfx[w] + (uint32_t)__popcll(kw & ((1ull << b) - 1ull));
            if (rank < MAXB) keepl[rank] = i;
        }
    }
}

// ---------------- gather output rows ----------------
__global__ __launch_bounds__(256) void k_out(const float* __restrict__ det,
                                             const uint32_t* __restrict__ topk,
                                             const int* __restrict__ keepl,
                                             float* __restrict__ out) {
    int t = blockIdx.x * 256 + threadIdx.x;
    if (t >= MAXB * DET_DIM) return;
    int r = t / DET_DIM, col = t - r * DET_DIM;
    int pos = keepl[r];
    float v = 0.0f;
    if (pos >= 0) v = det[(size_t)topk[pos] * DET_DIM + col];
    out[t] = v;
}

extern "C" void kernel_launch(void* const* d_in, const int* in_sizes, int n_in,
                              void* d_out, int out_size, void* d_ws, size_t ws_size,
                              hipStream_t stream) {
    const float4* boxes4 = (const float4*)d_in[0];
    const float4* cls4   = (const float4*)d_in[1];
    const float*  det    = (const float*)d_in[2];
    float* out = (float*)d_out;
    uint32_t* ws = (uint32_t*)d_ws;

    uint32_t* sbits = ws + OFF_SBITS;
    uint32_t* histA = ws + OFF_HISTA;
    uint32_t* histB = ws + OFF_HISTB;
    uint32_t* meta  = ws + OFF_META;
    unsigned long long* cand = (unsigned long long*)(ws + OFF_CAND);
    uint32_t* topk  = ws + OFF_TOPK;
    float4*   boxk  = (float4*)(ws + OFF_BOXK);
    unsigned long long* M = (unsigned long long*)(ws + OFF_MASK);
    int* keepl = (int*)(ws + OFF_KEEPL);

    // zero histA + histB + meta (contiguous)
    hipMemsetAsync(histA, 0, (4096 * 2 + 64) * sizeof(uint32_t), stream);

    k_scores<<<(N_ANCH + 63) / 64, 256, 0, stream>>>(cls4, sbits, histA);
    k_findthr<<<1, 1024, 0, stream>>>(histA, &meta[7], TOPK, &meta[0]);
    k_histB<<<(N_ANCH + 255) / 256, 256, 0, stream>>>(sbits, meta, histB);
    k_findthr<<<1, 1024, 0, stream>>>(histB, &meta[1], TOPK, &meta[2]);
    k_compact<<<(N_ANCH + 255) / 256, 256, 0, stream>>>(sbits, meta, cand, &meta[4]);
    k_sort<<<1, 1024, 0, stream>>>(cand, &meta[4], topk, boxes4, boxk);
    k_mask<<<(TOPK * 16) / 4, 256, 0, stream>>>(boxk, M);
    k_nms<<<1, 64, 0, stream>>>(M, keepl);
    k_out<<<(MAXB * DET_DIM + 255) / 256, 256, 0, stream>>>(det, topk, keepl, out);
}

// Round 2
// 396.531 us; speedup vs baseline: 1.1500x; 1.1500x over previous
//
#include <hip/hip_runtime.h>
#include <stdint.h>

#define N_ANCH   300000
#define N_CLS    80
#define DET_DIM  85
#define TOPK     1000
#define MAXB     300
#define NMS_THR  0.4f
#define CAP      4096

// ws layout (uint32 units)
#define OFF_SBITS   0          // 300000 u32
#define OFF_HISTA   300032     // 4096 u32
#define OFF_HISTB   304128     // 4096 u32
#define OFF_META    308224     // 64 u32: [0]=B_A [1]=G_A [2]=B_B [3]=G_B [4]=cand_cnt [7]=const zero
#define OFF_CAND    308352     // 4096 u64 = 8192 u32
#define OFF_TOPK    316544     // 1000 u32
#define OFF_BOXK    317568     // 1000 float4 = 4000 u32
#define OFF_MASK    321600     // 16000 u64 = 32000 u32
#define OFF_KEEPL   353600     // 300 int

// ---------------- scores = max over 80 classes + histogram A ----------------
__global__ __launch_bounds__(256) void k_scores(const float4* __restrict__ cls4,
                                                uint32_t* __restrict__ sbits,
                                                uint32_t* __restrict__ histA) {
    __shared__ uint32_t h[4096];
    int tid = threadIdx.x;
    for (int i = tid; i < 4096; i += 256) h[i] = 0;
    __syncthreads();
    int wave = tid >> 6, lane = tid & 63, g = lane >> 2, q = lane & 3;
    int row = blockIdx.x * 64 + wave * 16 + g;
    if (row < N_ANCH) {
        const float4* rp = cls4 + (size_t)row * 20;   // 80 floats = 20 float4
        float m = -1.0f;
        #pragma unroll
        for (int k = 0; k < 5; k++) {
            float4 v = rp[q + k * 4];
            m = fmaxf(m, fmaxf(fmaxf(v.x, v.y), fmaxf(v.z, v.w)));
        }
        m = fmaxf(m, __shfl_xor(m, 1));
        m = fmaxf(m, __shfl_xor(m, 2));
        if (q == 0) {
            uint32_t sb = __float_as_uint(m);   // scores >= 0: bit order == value order
            sbits[row] = sb;
            atomicAdd(&h[sb >> 20], 1u);
        }
    }
    __syncthreads();
    for (int i = tid; i < 4096; i += 256) {
        uint32_t c = h[i];
        if (c) atomicAdd(&histA[i], c);
    }
}

// ------------- find bin B s.t. suffix count crosses K; G = count above -------------
__global__ __launch_bounds__(1024) void k_findthr(const uint32_t* __restrict__ hist,
                                                  const uint32_t* __restrict__ gprev,
                                                  uint32_t Kbase,
                                                  uint32_t* __restrict__ out2) {
    __shared__ uint32_t part[1024];
    int tid = threadIdx.x;
    uint32_t c[4]; uint32_t s = 0;
    #pragma unroll
    for (int k = 0; k < 4; k++) { c[k] = hist[4095 - (tid * 4 + k)]; s += c[k]; }
    part[tid] = s;
    __syncthreads();
    for (int off = 1; off < 1024; off <<= 1) {
        uint32_t v = (tid >= off) ? part[tid - off] : 0;
        __syncthreads();
        part[tid] += v;
        __syncthreads();
    }
    uint32_t incl = part[tid], excl = incl - s;
    uint32_t K = Kbase - *gprev;
    if (excl < K && incl >= K) {
        uint32_t run = excl;
        #pragma unroll
        for (int k = 0; k < 4; k++) {
            uint32_t nr = run + c[k];
            if (run < K && nr >= K) { out2[0] = 4095 - (tid * 4 + k); out2[1] = run; }
            run = nr;
        }
    }
}

// ---------------- level-B histogram (bits[19:8] within bin B_A) ----------------
__global__ __launch_bounds__(256) void k_histB(const uint32_t* __restrict__ sbits,
                                               const uint32_t* __restrict__ meta,
                                               uint32_t* __restrict__ histB) {
    int t = blockIdx.x * 256 + threadIdx.x;
    if (t >= N_ANCH) return;
    uint32_t sb = sbits[t];
    if ((sb >> 20) == meta[0]) atomicAdd(&histB[(sb >> 8) & 0xFFFu], 1u);
}

// ---------------- compact candidates with 24-bit prefix >= T24 ----------------
__global__ __launch_bounds__(256) void k_compact(const uint32_t* __restrict__ sbits,
                                                 const uint32_t* __restrict__ meta,
                                                 unsigned long long* __restrict__ cand,
                                                 uint32_t* __restrict__ cnt) {
    int t = blockIdx.x * 256 + threadIdx.x;
    if (t >= N_ANCH) return;
    uint32_t T24 = (meta[0] << 12) | meta[2];
    uint32_t sb = sbits[t];
    if ((sb >> 8) >= T24) {
        uint32_t p = atomicAdd(cnt, 1u);
        if (p < CAP) cand[p] = ((unsigned long long)sb << 32) | (uint32_t)(~(uint32_t)t);
    }
}

// ---------------- exact rank by counting (replaces bitonic sort) ----------------
// keys are unique ((sb<<32)|~idx), all top-1000 are in cand (C >= 1000 by
// threshold construction), so rank_i = #{j: key_j > key_i} is the exact
// descending-sort position with jax's (value desc, index asc) tie-break.
__global__ __launch_bounds__(256) void k_rank(const unsigned long long* __restrict__ cand,
                                              const uint32_t* __restrict__ cnt,
                                              uint32_t* __restrict__ topk,
                                              const float4* __restrict__ boxes4,
                                              float4* __restrict__ boxk) {
    int t = blockIdx.x * 256 + threadIdx.x;
    uint32_t C = *cnt; if (C > CAP) C = CAP;
    if (t >= (int)C) return;
    unsigned long long my = cand[t];
    uint32_t rank = 0;
    int j = 0;
    for (; j + 8 <= (int)C; j += 8) {
        #pragma unroll
        for (int u = 0; u < 8; u++) rank += (cand[j + u] > my) ? 1u : 0u;
    }
    for (; j < (int)C; j++) rank += (cand[j] > my) ? 1u : 0u;
    if (rank < TOPK) {
        uint32_t idx = ~(uint32_t)(my & 0xFFFFFFFFull);
        topk[rank] = idx;
        boxk[rank] = boxes4[idx];
    }
}

// ---------------- IoU (fp32, no fma contraction, matches reference op order) ----------------
__device__ __forceinline__ float iou_f(float4 a, float4 b) {
    #pragma clang fp contract(off)
    // box = [y1, x1, y2, x2] -> (x,y,z,w)
    float areaA = (a.z - a.x) * (a.w - a.y);
    float areaB = (b.z - b.x) * (b.w - b.y);
    float ih = fminf(a.z, b.z) - fmaxf(a.x, b.x); ih = fmaxf(ih, 0.0f);
    float iw = fminf(a.w, b.w) - fmaxf(a.y, b.y); iw = fmaxf(iw, 0.0f);
    float inter = ih * iw;
    float denom = (areaA + areaB - inter) + 1e-8f;
    return inter / denom;
}

// ---------------- suppression bitmask M[i][w]: bit j = iou(i, w*64+j) > thr ----------------
__global__ __launch_bounds__(256) void k_mask(const float4* __restrict__ boxk,
                                              unsigned long long* __restrict__ M) {
    int tid = threadIdx.x;
    int gw = blockIdx.x * 4 + (tid >> 6);   // global wave id: 1000 rows * 16 words
    int i = gw >> 4, w = gw & 15, jl = tid & 63;
    int j = w * 64 + jl;
    float4 bi = boxk[i];
    float4 bj = boxk[j < TOPK ? j : 0];
    bool ok = (j < TOPK) && (iou_f(bi, bj) > NMS_THR);
    unsigned long long m = __ballot(ok);
    if (jl == 0) M[i * 16 + w] = m;
}

// ---------------- sequential greedy NMS scan (single wave, ballot-reconstruction) ----------------
// Intra-chunk: by IoU symmetry, row k of the 64x64 intra-chunk matrix equals
// column k, which is exactly __ballot((Mic >> k) & 1) over the lanes' own rows.
// Loop-carried state (kc) is wave-uniform -> pure SALU chain, no shuffles.
__global__ __launch_bounds__(64) void k_nms(const unsigned long long* __restrict__ M,
                                            int* __restrict__ keepl) {
    int lane = threadIdx.x;
    unsigned long long keptArr[16];
    #pragma unroll
    for (int c = 0; c < 16; c++) {
        int i = c * 64 + lane;
        unsigned long long pre = 0ull;
        unsigned long long Mic = 0ull;
        if (i < TOPK) {
            #pragma unroll
            for (int w = 0; w < c; w++) pre |= M[i * 16 + w] & keptArr[w];  // keptArr[w<c] final
            Mic = M[i * 16 + c];
        }
        unsigned long long pre_mask = __ballot(pre != 0ull);
        unsigned long long kc = 0ull;
        const int lim = (c == 15) ? (TOPK - 960) : 64;
        for (int k = 0; k < lim; k++) {
            unsigned long long b = __ballot(((Mic >> k) & 1ull) != 0ull);  // = row k of chunk
            bool sup = (((pre_mask >> k) & 1ull) != 0ull) || ((b & kc) != 0ull);
            kc |= sup ? 0ull : (1ull << k);
        }
        keptArr[c] = kc;
    }
    // prefix ranks (all values wave-uniform; every lane computes the same)
    uint32_t pfxw[16];
    uint32_t run = 0;
    #pragma unroll
    for (int w = 0; w < 16; w++) { pfxw[w] = run; run += (uint32_t)__popcll(keptArr[w]); }
    int total = (int)run; if (total > MAXB) total = MAXB;
    for (int r = total + lane; r < MAXB; r += 64) keepl[r] = -1;   // disjoint from rank writes
    #pragma unroll
    for (int w = 0; w < 16; w++) {
        int i = w * 64 + lane;
        if (i < TOPK) {
            unsigned long long kw = keptArr[w];
            if ((kw >> lane) & 1ull) {
                uint32_t rank = pfxw[w] + (uint32_t)__popcll(kw & ((1ull << lane) - 1ull));
                if (rank < MAXB) keepl[rank] = i;
            }
        }
    }
}

// ---------------- gather output rows ----------------
__global__ __launch_bounds__(256) void k_out(const float* __restrict__ det,
                                             const uint32_t* __restrict__ topk,
                                             const int* __restrict__ keepl,
                                             float* __restrict__ out) {
    int t = blockIdx.x * 256 + threadIdx.x;
    if (t >= MAXB * DET_DIM) return;
    int r = t / DET_DIM, col = t - r * DET_DIM;
    int pos = keepl[r];
    float v = 0.0f;
    if (pos >= 0) v = det[(size_t)topk[pos] * DET_DIM + col];
    out[t] = v;
}

extern "C" void kernel_launch(void* const* d_in, const int* in_sizes, int n_in,
                              void* d_out, int out_size, void* d_ws, size_t ws_size,
                              hipStream_t stream) {
    const float4* boxes4 = (const float4*)d_in[0];
    const float4* cls4   = (const float4*)d_in[1];
    const float*  det    = (const float*)d_in[2];
    float* out = (float*)d_out;
    uint32_t* ws = (uint32_t*)d_ws;

    uint32_t* sbits = ws + OFF_SBITS;
    uint32_t* histA = ws + OFF_HISTA;
    uint32_t* histB = ws + OFF_HISTB;
    uint32_t* meta  = ws + OFF_META;
    unsigned long long* cand = (unsigned long long*)(ws + OFF_CAND);
    uint32_t* topk  = ws + OFF_TOPK;
    float4*   boxk  = (float4*)(ws + OFF_BOXK);
    unsigned long long* M = (unsigned long long*)(ws + OFF_MASK);
    int* keepl = (int*)(ws + OFF_KEEPL);

    // zero histA + histB + meta (contiguous)
    hipMemsetAsync(histA, 0, (4096 * 2 + 64) * sizeof(uint32_t), stream);

    k_scores<<<(N_ANCH + 63) / 64, 256, 0, stream>>>(cls4, sbits, histA);
    k_findthr<<<1, 1024, 0, stream>>>(histA, &meta[7], TOPK, &meta[0]);
    k_histB<<<(N_ANCH + 255) / 256, 256, 0, stream>>>(sbits, meta, histB);
    k_findthr<<<1, 1024, 0, stream>>>(histB, &meta[1], TOPK, &meta[2]);
    k_compact<<<(N_ANCH + 255) / 256, 256, 0, stream>>>(sbits, meta, cand, &meta[4]);
    k_rank<<<CAP / 256, 256, 0, stream>>>(cand, &meta[4], topk, boxes4, boxk);
    k_mask<<<(TOPK * 16) / 4, 256, 0, stream>>>(boxk, M);
    k_nms<<<1, 64, 0, stream>>>(M, keepl);
    k_out<<<(MAXB * DET_DIM + 255) / 256, 256, 0, stream>>>(det, topk, keepl, out);
}

// Round 3
// 363.911 us; speedup vs baseline: 1.2531x; 1.0896x over previous
//
#include <hip/hip_runtime.h>
#include <stdint.h>

#define N_ANCH   300000
#define N_CLS    80
#define DET_DIM  85
#define TOPK     1000
#define MAXB     300
#define NMS_THR  0.4f
#define CAP      4096
#define NB       16                      // grid-stride blocks for hist/compact passes
#define ITERS    ((N_ANCH + NB*256 - 1) / (NB*256))

// ws layout (uint32 units). PART is dead after k_findthr(B); CAND..KEEPL alias it.
#define OFF_SBITS   0          // 300000 u32
#define OFF_PART    300032     // 16*4096 = 65536 u32 (partials, reused for A then B)
#define OFF_CAND    300032     // 4096 u64 = 8192 u32   (aliases PART — PART dead)
#define OFF_TOPK    308224     // 1000 u32
#define OFF_BOXK    309224     // 1000 float4 = 4000 u32 (byte off %16 == 0)
#define OFF_MASK    313224     // 16000 u64 = 32000 u32  (byte off %8 == 0)
#define OFF_KEEPL   345224     // 300 int
#define OFF_META    365568     // 64 u32: [0]=B_A [1]=G_A [2]=B_B [3]=G_B [4]=cand_cnt [7]=zero

// ---------------- scores = max over 80 classes (pure BW pass) ----------------
__global__ __launch_bounds__(256) void k_scores(const float4* __restrict__ cls4,
                                                uint32_t* __restrict__ sbits) {
    int tid = threadIdx.x;
    int wave = tid >> 6, lane = tid & 63, g = lane >> 2, q = lane & 3;
    int row = blockIdx.x * 64 + wave * 16 + g;
    if (row >= N_ANCH) return;
    const float4* rp = cls4 + (size_t)row * 20;   // 80 floats = 20 float4
    float m = -1.0f;
    #pragma unroll
    for (int k = 0; k < 5; k++) {
        float4 v = rp[q + k * 4];
        m = fmaxf(m, fmaxf(fmaxf(v.x, v.y), fmaxf(v.z, v.w)));
    }
    m = fmaxf(m, __shfl_xor(m, 1));
    m = fmaxf(m, __shfl_xor(m, 2));
    if (q == 0) sbits[row] = __float_as_uint(m);  // scores >= 0: bit order == value order
}

// ---------------- level-A histogram: LDS + ballot-aggregated adds, partial out ----------------
// Distribution is degenerate (~99% of anchors share one 12-bit bin), so aggregate
// same-bin lanes per wave via ballot: ~2 LDS atomics/wave instead of 64 same-address.
__global__ __launch_bounds__(256) void k_histA(const uint32_t* __restrict__ sbits,
                                               uint32_t* __restrict__ part) {
    __shared__ uint32_t h[4096];
    int tid = threadIdx.x, lane = tid & 63;
    for (int i = tid; i < 4096; i += 256) h[i] = 0;
    __syncthreads();
    for (int it = 0; it < ITERS; it++) {
        int t = it * (NB * 256) + blockIdx.x * 256 + tid;
        bool valid = t < N_ANCH;
        uint32_t bin = valid ? (sbits[t] >> 20) : 0u;
        bool done = !valid;
        while (true) {
            unsigned long long rem = __ballot(!done);
            if (rem == 0ull) break;
            int leader = __ffsll((long long)rem) - 1;
            uint32_t lbin = __shfl(bin, leader);
            bool mine = (!done) && (bin == lbin);
            unsigned long long grp = __ballot(mine);
            if (lane == leader) atomicAdd(&h[lbin], (uint32_t)__popcll(grp));
            done = done || mine;
        }
    }
    __syncthreads();
    for (int i = tid; i < 4096; i += 256) part[blockIdx.x * 4096 + i] = h[i];
}

// ---------------- level-B histogram (bits[19:8] within bin B_A), partial out ----------------
// Within-bin values spread over 4096 sub-bins -> plain LDS atomics are near conflict-free.
__global__ __launch_bounds__(256) void k_histB(const uint32_t* __restrict__ sbits,
                                               const uint32_t* __restrict__ meta,
                                               uint32_t* __restrict__ part) {
    __shared__ uint32_t h[4096];
    int tid = threadIdx.x;
    for (int i = tid; i < 4096; i += 256) h[i] = 0;
    __syncthreads();
    uint32_t binA = meta[0];
    for (int it = 0; it < ITERS; it++) {
        int t = it * (NB * 256) + blockIdx.x * 256 + tid;
        if (t < N_ANCH) {
            uint32_t sb = sbits[t];
            if ((sb >> 20) == binA) atomicAdd(&h[(sb >> 8) & 0xFFFu], 1u);
        }
    }
    __syncthreads();
    for (int i = tid; i < 4096; i += 256) part[blockIdx.x * 4096 + i] = h[i];
}

// ------- reduce NB partials + find bin where suffix count crosses K; G = count above -------
__global__ __launch_bounds__(1024) void k_findthr(const uint32_t* __restrict__ part,
                                                  const uint32_t* __restrict__ gprev,
                                                  uint32_t Kbase,
                                                  uint32_t* __restrict__ out2) {
    __shared__ uint32_t ps[1024];
    int tid = threadIdx.x;
    uint32_t c[4]; uint32_t s = 0;
    #pragma unroll
    for (int k = 0; k < 4; k++) {
        int bin = 4095 - (tid * 4 + k);
        uint32_t v = 0;
        #pragma unroll
        for (int r = 0; r < NB; r++) v += part[r * 4096 + bin];
        c[k] = v; s += v;
    }
    ps[tid] = s;
    __syncthreads();
    for (int off = 1; off < 1024; off <<= 1) {
        uint32_t v = (tid >= off) ? ps[tid - off] : 0;
        __syncthreads();
        ps[tid] += v;
        __syncthreads();
    }
    uint32_t incl = ps[tid], excl = incl - s;
    uint32_t K = Kbase - *gprev;
    if (excl < K && incl >= K) {
        uint32_t run = excl;
        #pragma unroll
        for (int k = 0; k < 4; k++) {
            uint32_t nr = run + c[k];
            if (run < K && nr >= K) { out2[0] = 4095 - (tid * 4 + k); out2[1] = run; }
            run = nr;
        }
    }
}

// ---------------- compact candidates (24-bit prefix >= T24), two-phase, 1 atomic/block ----------------
__global__ __launch_bounds__(256) void k_compact(const uint32_t* __restrict__ sbits,
                                                 const uint32_t* __restrict__ meta,
                                                 unsigned long long* __restrict__ cand,
                                                 uint32_t* __restrict__ cnt) {
    __shared__ uint32_t wsum[4];
    int tid = threadIdx.x, wave = tid >> 6, lane = tid & 63;
    uint32_t T24 = (meta[0] << 12) | meta[2];
    // phase 1: per-wave counts
    uint32_t cw = 0;
    for (int it = 0; it < ITERS; it++) {
        int t = it * (NB * 256) + blockIdx.x * 256 + tid;
        bool m = (t < N_ANCH) && ((sbits[t] >> 8) >= T24);
        unsigned long long b = __ballot(m);
        cw += (uint32_t)__popcll(b);
    }
    if (lane == 0) wsum[wave] = cw;
    __syncthreads();
    if (tid == 0) {
        uint32_t tot = wsum[0] + wsum[1] + wsum[2] + wsum[3];
        uint32_t base = atomicAdd(cnt, tot);
        uint32_t r = base;
        #pragma unroll
        for (int w = 0; w < 4; w++) { uint32_t c0 = wsum[w]; wsum[w] = r; r += c0; }
    }
    __syncthreads();
    uint32_t wbase = wsum[wave];
    // phase 2: ordered-slot writes (order within cand is irrelevant; rank fixes it)
    for (int it = 0; it < ITERS; it++) {
        int t = it * (NB * 256) + blockIdx.x * 256 + tid;
        uint32_t sb = (t < N_ANCH) ? sbits[t] : 0u;
        bool m = (t < N_ANCH) && ((sb >> 8) >= T24);
        unsigned long long b = __ballot(m);
        if (m) {
            uint32_t p = wbase + (uint32_t)__popcll(b & ((1ull << lane) - 1ull));
            if (p < CAP) cand[p] = ((unsigned long long)sb << 32) | (uint32_t)(~(uint32_t)t);
        }
        wbase += (uint32_t)__popcll(b);
    }
}

// ---------------- exact rank by counting ----------------
// keys unique ((sb<<32)|~idx); all top-1000 are in cand (C >= 1000 by construction);
// rank = #{j: key_j > key_i} reproduces jax's (value desc, index asc) order exactly.
__global__ __launch_bounds__(256) void k_rank(const unsigned long long* __restrict__ cand,
                                              const uint32_t* __restrict__ cnt,
                                              uint32_t* __restrict__ topk,
                                              const float4* __restrict__ boxes4,
                                              float4* __restrict__ boxk) {
    int t = blockIdx.x * 256 + threadIdx.x;
    uint32_t C = *cnt; if (C > CAP) C = CAP;
    if (t >= (int)C) return;
    unsigned long long my = cand[t];
    uint32_t rank = 0;
    int j = 0;
    for (; j + 8 <= (int)C; j += 8) {
        #pragma unroll
        for (int u = 0; u < 8; u++) rank += (cand[j + u] > my) ? 1u : 0u;
    }
    for (; j < (int)C; j++) rank += (cand[j] > my) ? 1u : 0u;
    if (rank < TOPK) {
        uint32_t idx = ~(uint32_t)(my & 0xFFFFFFFFull);
        topk[rank] = idx;
        boxk[rank] = boxes4[idx];
    }
}

// ---------------- IoU (fp32, no fma contraction, matches reference op order) ----------------
__device__ __forceinline__ float iou_f(float4 a, float4 b) {
    #pragma clang fp contract(off)
    // box = [y1, x1, y2, x2] -> (x,y,z,w)
    float areaA = (a.z - a.x) * (a.w - a.y);
    float areaB = (b.z - b.x) * (b.w - b.y);
    float ih = fminf(a.z, b.z) - fmaxf(a.x, b.x); ih = fmaxf(ih, 0.0f);
    float iw = fminf(a.w, b.w) - fmaxf(a.y, b.y); iw = fmaxf(iw, 0.0f);
    float inter = ih * iw;
    float denom = (areaA + areaB - inter) + 1e-8f;
    return inter / denom;
}

// ---------------- suppression bitmask M[i][w]: bit j = iou(i, w*64+j) > thr ----------------
__global__ __launch_bounds__(256) void k_mask(const float4* __restrict__ boxk,
                                              unsigned long long* __restrict__ M) {
    int tid = threadIdx.x;
    int gw = blockIdx.x * 4 + (tid >> 6);   // global wave id: 1000 rows * 16 words
    int i = gw >> 4, w = gw & 15, jl = tid & 63;
    int j = w * 64 + jl;
    float4 bi = boxk[i];
    float4 bj = boxk[j < TOPK ? j : 0];
    bool ok = (j < TOPK) && (iou_f(bi, bj) > NMS_THR);
    unsigned long long m = __ballot(ok);
    if (jl == 0) M[i * 16 + w] = m;
}

// ---------------- sequential greedy NMS scan (single wave, ballot-reconstruction) ----------------
__global__ __launch_bounds__(64) void k_nms(const unsigned long long* __restrict__ M,
                                            int* __restrict__ keepl) {
    int lane = threadIdx.x;
    unsigned long long keptArr[16];
    #pragma unroll
    for (int c = 0; c < 16; c++) {
        int i = c * 64 + lane;
        unsigned long long pre = 0ull;
        unsigned long long Mic = 0ull;
        if (i < TOPK) {
            #pragma unroll
            for (int w = 0; w < c; w++) pre |= M[i * 16 + w] & keptArr[w];  // keptArr[w<c] final
            Mic = M[i * 16 + c];
        }
        unsigned long long pre_mask = __ballot(pre != 0ull);
        unsigned long long kc = 0ull;
        const int lim = (c == 15) ? (TOPK - 960) : 64;
        for (int k = 0; k < lim; k++) {
            unsigned long long b = __ballot(((Mic >> k) & 1ull) != 0ull);  // = row k of chunk (IoU symmetry)
            bool sup = (((pre_mask >> k) & 1ull) != 0ull) || ((b & kc) != 0ull);
            kc |= sup ? 0ull : (1ull << k);
        }
        keptArr[c] = kc;
    }
    uint32_t pfxw[16];
    uint32_t run = 0;
    #pragma unroll
    for (int w = 0; w < 16; w++) { pfxw[w] = run; run += (uint32_t)__popcll(keptArr[w]); }
    int total = (int)run; if (total > MAXB) total = MAXB;
    for (int r = total + lane; r < MAXB; r += 64) keepl[r] = -1;   // disjoint from rank writes
    #pragma unroll
    for (int w = 0; w < 16; w++) {
        int i = w * 64 + lane;
        if (i < TOPK) {
            unsigned long long kw = keptArr[w];
            if ((kw >> lane) & 1ull) {
                uint32_t rank = pfxw[w] + (uint32_t)__popcll(kw & ((1ull << lane) - 1ull));
                if (rank < MAXB) keepl[rank] = i;
            }
        }
    }
}

// ---------------- gather output rows ----------------
__global__ __launch_bounds__(256) void k_out(const float* __restrict__ det,
                                             const uint32_t* __restrict__ topk,
                                             const int* __restrict__ keepl,
                                             float* __restrict__ out) {
    int t = blockIdx.x * 256 + threadIdx.x;
    if (t >= MAXB * DET_DIM) return;
    int r = t / DET_DIM, col = t - r * DET_DIM;
    int pos = keepl[r];
    float v = 0.0f;
    if (pos >= 0) v = det[(size_t)topk[pos] * DET_DIM + col];
    out[t] = v;
}

extern "C" void kernel_launch(void* const* d_in, const int* in_sizes, int n_in,
                              void* d_out, int out_size, void* d_ws, size_t ws_size,
                              hipStream_t stream) {
    const float4* boxes4 = (const float4*)d_in[0];
    const float4* cls4   = (const float4*)d_in[1];
    const float*  det    = (const float*)d_in[2];
    float* out = (float*)d_out;
    uint32_t* ws = (uint32_t*)d_ws;

    uint32_t* sbits = ws + OFF_SBITS;
    uint32_t* part  = ws + OFF_PART;
    uint32_t* meta  = ws + OFF_META;
    unsigned long long* cand = (unsigned long long*)(ws + OFF_CAND);
    uint32_t* topk  = ws + OFF_TOPK;
    float4*   boxk  = (float4*)(ws + OFF_BOXK);
    unsigned long long* M = (unsigned long long*)(ws + OFF_MASK);
    int* keepl = (int*)(ws + OFF_KEEPL);

    hipMemsetAsync(meta, 0, 64 * sizeof(uint32_t), stream);

    k_scores <<<(N_ANCH + 63) / 64, 256, 0, stream>>>(cls4, sbits);
    k_histA  <<<NB, 256, 0, stream>>>(sbits, part);
    k_findthr<<<1, 1024, 0, stream>>>(part, &meta[7], TOPK, &meta[0]);
    k_histB  <<<NB, 256, 0, stream>>>(sbits, meta, part);
    k_findthr<<<1, 1024, 0, stream>>>(part, &meta[1], TOPK, &meta[2]);
    k_compact<<<NB, 256, 0, stream>>>(sbits, meta, cand, &meta[4]);
    k_rank   <<<CAP / 256, 256, 0, stream>>>(cand, &meta[4], topk, boxes4, boxk);
    k_mask   <<<(TOPK * 16) / 4, 256, 0, stream>>>(boxk, M);
    k_nms    <<<1, 64, 0, stream>>>(M, keepl);
    k_out    <<<(MAXB * DET_DIM + 255) / 256, 256, 0, stream>>>(det, topk, keepl, out);
}